// Round 13
// baseline (237.162 us; speedup 1.0000x reference)
//
#include <hip/hip_runtime.h>
#include <hip/hip_bf16.h>
#include <math.h>

typedef __attribute__((ext_vector_type(8))) short short8;
typedef __attribute__((ext_vector_type(4))) float floatx4;
typedef __attribute__((ext_vector_type(16))) float floatx16;

#define B_ 8
#define C_ 256
#define N_ 4096
#define LOG2E 1.4426950408889634f
#define VSTRIDE 80    // attn K-LDS row stride (32 bf16 + pad)
#define XSTRIDE 532   // qkv LDS row stride bytes (256 bf16 + 20B pad)

static __device__ __forceinline__ unsigned short f2bf(float f) {
  union { float f; unsigned int u; } v; v.f = f;
  unsigned int u = v.u;
  u += 0x7FFFu + ((u >> 16) & 1u);   // RNE
  return (unsigned short)(u >> 16);
}
static __device__ __forceinline__ float bf2f(unsigned short h) {
  union { unsigned int u; float f; } v; v.u = ((unsigned int)h) << 16; return v.f;
}
// truncation pack of two positive f32 -> bf16x2 in ONE v_perm_b32 (lo = a, hi = b)
static __device__ __forceinline__ unsigned int pk2(float a, float b) {
  return __builtin_amdgcn_perm(__float_as_uint(b), __float_as_uint(a), 0x07060302u);
}

// ---------------- kernel 0: weight convert + ssq zero ----------------
__global__ void prep_kernel(const float* __restrict__ Wq, const float* __restrict__ Wk,
                            const float* __restrict__ Wv,
                            unsigned short* __restrict__ wqb, unsigned short* __restrict__ wkb,
                            unsigned short* __restrict__ wvb, float* __restrict__ ssq) {
  int t = blockIdx.x * 256 + threadIdx.x;
  if (t < 512) ssq[t] = 0.0f;
  if (t < 8192) { wqb[t] = f2bf(Wq[t]); wkb[t] = f2bf(Wk[t]); }
  int tv = t - 8192;
  if (tv >= 0 && tv < 65536) wvb[tv] = f2bf(Wv[tv]);
}

// ---------------- kernel 1: QKV GEMM, coalesced transpose-staged x ----------------
// V written in FRAGMENT-NATIVE tiled layout: elem[(n>>3)*2048 + cv*8 + (n&7)]
__launch_bounds__(256, 2)
__global__ void qkv_kernel(const float* __restrict__ x,
                           const unsigned short* __restrict__ wqb,
                           const unsigned short* __restrict__ wkb,
                           const unsigned short* __restrict__ wvb,
                           const float* __restrict__ bq, const float* __restrict__ bk,
                           const float* __restrict__ bv,
                           unsigned short* __restrict__ qbf, unsigned short* __restrict__ kbf,
                           unsigned short* __restrict__ vbf, float* __restrict__ ssq) {
  __shared__ __align__(16) char Xt[64 * XSTRIDE];   // [64 n][256 c bf16 + pad]
  int b = blockIdx.x & 7;
  int nblk = blockIdx.x >> 3;
  int tid = threadIdx.x;
  int w = tid >> 6, lane = tid & 63;
  int r = lane & 15, g = lane >> 4;
  int n0 = nblk * 64;
  int q = tid & 15, cpl = tid >> 4;

  // ---- stage x tile: [c][n] fp32 -> [n][c] bf16 (transpose via regs) ----
  const float* xb = x + ((size_t)b << 20) + n0 + q * 4;
  #pragma unroll
  for (int p = 0; p < 8; ++p) {
    int cp = p * 16 + cpl;                         // c-pair index: c = 2cp, 2cp+1
    const float* s0 = xb + ((size_t)(2 * cp) << 12);
    float4 a  = *(const float4*)s0;
    float4 bb = *(const float4*)(s0 + 4096);
    char* dst = Xt + cp * 4;
    *(unsigned int*)(dst + (q * 4 + 0) * XSTRIDE) = pk2(a.x, bb.x);
    *(unsigned int*)(dst + (q * 4 + 1) * XSTRIDE) = pk2(a.y, bb.y);
    *(unsigned int*)(dst + (q * 4 + 2) * XSTRIDE) = pk2(a.z, bb.z);
    *(unsigned int*)(dst + (q * 4 + 3) * XSTRIDE) = pk2(a.w, bb.w);
  }
  __syncthreads();

  // ---- fragments: B[k=c][col=n], lane col = n0 + w*16 + r, k = ks*32 + g*8 + j ----
  short8 xf[8];
  #pragma unroll
  for (int ks = 0; ks < 8; ++ks) {
    const char* src = Xt + (w * 16 + r) * XSTRIDE + (ks * 32 + g * 8) * 2;
    union { unsigned int u[4]; short8 s8; } t;
    t.u[0] = *(const unsigned int*)(src);
    t.u[1] = *(const unsigned int*)(src + 4);
    t.u[2] = *(const unsigned int*)(src + 8);
    t.u[3] = *(const unsigned int*)(src + 12);
    xf[ks] = t.s8;
  }
  int nw = n0 + w * 16;
  floatx4 zero = {0.f, 0.f, 0.f, 0.f};

  // ---- V: 16 output tiles, tiled-layout writes ----
  unsigned short* vt = vbf + (size_t)b * C_ * N_;
  #pragma unroll 2
  for (int ot = 0; ot < 16; ++ot) {
    floatx4 acc = zero;
    #pragma unroll
    for (int ks = 0; ks < 8; ++ks) {
      short8 af = *(const short8*)&wvb[(ot * 16 + r) * 256 + ks * 32 + g * 8];
      acc = __builtin_amdgcn_mfma_f32_16x16x32_bf16(af, xf[ks], acc, 0, 0, 0);
    }
    #pragma unroll
    for (int rr = 0; rr < 4; ++rr) {
      int oc = ot * 16 + g * 4 + rr;
      int n = nw + r;
      vt[(size_t)(n >> 3) * 2048 + oc * 8 + (n & 7)] = f2bf(acc[rr] + bv[oc]);
    }
  }
  // ---- Q then K (2 tiles each), RAW (normalization folded into attn) ----
  #pragma unroll 1
  for (int qk = 0; qk < 2; ++qk) {
    const unsigned short* wb = qk ? wkb : wqb;
    const float* bias = qk ? bk : bq;
    unsigned short* dst = qk ? kbf : qbf;
    int sbase = qk ? 256 : 0;
    #pragma unroll 2
    for (int ot = 0; ot < 2; ++ot) {
      floatx4 acc = zero;
      #pragma unroll
      for (int ks = 0; ks < 8; ++ks) {
        short8 af = *(const short8*)&wb[(ot * 16 + r) * 256 + ks * 32 + g * 8];
        acc = __builtin_amdgcn_mfma_f32_16x16x32_bf16(af, xf[ks], acc, 0, 0, 0);
      }
      #pragma unroll
      for (int rr = 0; rr < 4; ++rr) {
        int oc = ot * 16 + g * 4 + rr;
        float val = acc[rr] + bias[oc];
        dst[(size_t)(b * N_ + nw + r) * 32 + oc] = f2bf(val);
        float s = val * val;               // reduce over the 16 n (lanes r)
        s += __shfl_xor(s, 1);
        s += __shfl_xor(s, 2);
        s += __shfl_xor(s, 4);
        s += __shfl_xor(s, 8);
        if (r == 0) atomicAdd(&ssq[sbase + b * 32 + oc], s);
      }
    }
  }
}

// ---------------- kernel 2: 32x32-MFMA attention, m=64, 2 blocks/CU ----------------
// r12 structure with the block halved: grid 512 (b 8 x mblk 64), 8 waves = ms(2) x cvh(4),
// each wave owns 64 v-channels (acc[2] = 32 regs). Two blocks co-reside per CU so the
// per-tile barrier drains interleave (r12 was 1 block/CU, ~75% idle). V traffic/block
// halves the amortization (1 GB L2 total ~ 10 TB/s, well under ceiling).
__launch_bounds__(512, 4)
__global__ void attn_kernel(const unsigned short* __restrict__ qbf,
                            const unsigned short* __restrict__ kbf,
                            const unsigned short* __restrict__ vbf,
                            const float* __restrict__ ssq, const float* __restrict__ temp,
                            const float* __restrict__ x, const float* __restrict__ gamma,
                            float* __restrict__ out) {
  __shared__ __align__(16) char Kt[2][32 * VSTRIDE];    // [buf][32 n][32 ch + pad]
  int b = blockIdx.x & 7, mblk = blockIdx.x >> 3;       // mblk in [0,64)
  int tid = threadIdx.x;
  int w = tid >> 6, lane = tid & 63, c = lane & 31, h = lane >> 5;
  int ms = w & 1, cvh = w >> 1;                         // ms: m-slice, cvh: 64-ch quarter
  const unsigned short* qb = qbf + (size_t)b * N_ * 32;
  const unsigned short* kb = kbf + (size_t)b * N_ * 32;
  const unsigned short* vt = vbf + (size_t)b * C_ * N_;
  int mrow = mblk * 64 + ms * 32 + c;                   // this lane's global m (column)
  int tdiag = mblk * 2 + ms;

  // ---- Q fragments with folded per-channel scale: invt*log2e/(||q_c||*||k_c||) ----
  float invt = LOG2E / (temp[0] + 1e-6f);
  short8 q0r = *(const short8*)&qb[mrow * 32 + h * 8];
  short8 q1r = *(const short8*)&qb[mrow * 32 + 16 + h * 8];
  short8 qf0, qf1;
  #pragma unroll
  for (int j = 0; j < 8; ++j) {
    int ch0 = h * 8 + j, ch1 = 16 + h * 8 + j;
    float s0 = invt * rsqrtf(fmaxf(ssq[b * 32 + ch0] * ssq[256 + b * 32 + ch0], 1e-24f));
    float s1 = invt * rsqrtf(fmaxf(ssq[b * 32 + ch1] * ssq[256 + b * 32 + ch1], 1e-24f));
    ((unsigned short*)&qf0)[j] = f2bf(bf2f(((const unsigned short*)&q0r)[j]) * s0);
    ((unsigned short*)&qf1)[j] = f2bf(bf2f(((const unsigned short*)&q1r)[j]) * s1);
  }

  // K staging (tid<128 stage 32n x 32ch = 2KB)
  int krow = tid >> 2, kq = tid & 3;
  const unsigned short* ksrc = kb + krow * 32 + kq * 8;
  int kwr = krow * VSTRIDE + kq * 16;

  // V fragment pointers (tiled layout): lane (c,h) of wave (cvh):
  // vp(t16) = vt + t16*4096 + h*2048 + (cvh*64 + c)*8 ; load += t*8192 + cvt*256 (512B imm)
  const unsigned short* vp0 = vt + h * 2048 + (cvh * 64 + c) * 8;
  const unsigned short* vp1 = vp0 + 4096;

  floatx16 zero16 = {0,0,0,0,0,0,0,0,0,0,0,0,0,0,0,0};
  floatx16 minit;                                        // C-init = -2*log2e (softmax shift)
  #pragma unroll
  for (int i = 0; i < 16; ++i) minit[i] = -2.0f * LOG2E;
  floatx16 acc[2] = {zero16, zero16};                    // [cvt] D[cv 32][m 32]
  float Lp = 0.0f;
  short8 kreg;
  short8 afA[4], afB[4];                                 // [t16*2+cvt] V frags, dbuf

  // prologue: K(0) -> LDS buf0; af(0) -> afA; K(1) -> kreg
  if (tid < 128) { kreg = *(const short8*)ksrc; *(short8*)(Kt[0] + kwr) = kreg; }
  #pragma unroll
  for (int k = 0; k < 4; ++k)
    afA[k] = *(const short8*)(((k >> 1) ? vp1 : vp0) + (k & 1) * 256);
  __syncthreads();
  if (tid < 128) kreg = *(const short8*)(ksrc + 1024);

  auto body = [&](int t, short8 (&afC)[4], short8 (&afN)[4]) {
    int t1 = t + 1;
    int tw = t1 & 127;
    // prefetch V(t+1) into afN: 4 coalesced loads
    #pragma unroll
    for (int k = 0; k < 4; ++k)
      afN[k] = *(const short8*)(((k >> 1) ? vp1 : vp0) + tw * 8192 + (k & 1) * 256);
    // QK^T from Kt[t&1]
    const char* Kb = Kt[t & 1];
    short8 kf0 = *(const short8*)(Kb + c * VSTRIDE + h * 16);
    short8 kf1 = *(const short8*)(Kb + c * VSTRIDE + 32 + h * 16);
    floatx16 s = __builtin_amdgcn_mfma_f32_32x32x16_bf16(kf0, qf0, minit, 0, 0, 0);
    s = __builtin_amdgcn_mfma_f32_32x32x16_bf16(kf1, qf1, s, 0, 0, 0);
    if (t == tdiag && ((c >> 2) & 1) == h)              // +I where global n == m
      s[(c & 3) | ((c >> 3) << 2)] += LOG2E;
    float p[16];
    float ls = 0.0f;
    #pragma unroll
    for (int i = 0; i < 16; ++i) {
      p[i] = __builtin_amdgcn_exp2f(s[i]);
      ls += p[i];
    }
    Lp += ls;
    #pragma unroll
    for (int t16 = 0; t16 < 2; ++t16) {
      unsigned int q0 = pk2(p[8*t16+0], p[8*t16+1]);
      unsigned int q1 = pk2(p[8*t16+2], p[8*t16+3]);
      unsigned int q2 = pk2(p[8*t16+4], p[8*t16+5]);
      unsigned int q3 = pk2(p[8*t16+6], p[8*t16+7]);
      // swap(vdst,vsrc): vdst[0:31] <-> vsrc[32:63]
      asm volatile("v_permlane32_swap_b32 %0, %1" : "+v"(q2), "+v"(q0));
      asm volatile("v_permlane32_swap_b32 %0, %1" : "+v"(q3), "+v"(q1));
      union { unsigned int u[4]; short8 s8; } bf;
      bf.u[0] = q0; bf.u[1] = q1; bf.u[2] = q2; bf.u[3] = q3;
      #pragma unroll
      for (int cvt = 0; cvt < 2; ++cvt)
        acc[cvt] = __builtin_amdgcn_mfma_f32_32x32x16_bf16(afC[t16 * 2 + cvt], bf.s8, acc[cvt], 0, 0, 0);
    }
    // K rotate: commit K(t+1), barrier, issue K(t+2)
    if (t1 < 128 && tid < 128) *(short8*)(Kt[t1 & 1] + kwr) = kreg;
    __syncthreads();
    if (t + 2 < 128 && tid < 128) kreg = *(const short8*)(ksrc + (size_t)(t + 2) * 1024);
  };

  #pragma unroll 1
  for (int t = 0; t < 128; t += 2) { body(t, afA, afB); body(t + 1, afB, afA); }

  // denominator: lane holds half the n-sum for column m; partner (lane^32) has the rest
  Lp += __shfl_xor(Lp, 32);
  float linv = 1.0f / Lp;
  float gam = gamma[0];
  #pragma unroll
  for (int cvt = 0; cvt < 2; ++cvt)
    #pragma unroll
    for (int i = 0; i < 16; ++i) {
      int cv = cvh * 64 + cvt * 32 + (i & 3) + 8 * (i >> 2) + 4 * h;
      size_t idx = ((size_t)(b * C_ + cv) << 12) + mrow;
      out[idx] = gam * acc[cvt][i] * linv + x[idx];
    }
}

extern "C" void kernel_launch(void* const* d_in, const int* in_sizes, int n_in,
                              void* d_out, int out_size, void* d_ws, size_t ws_size,
                              hipStream_t stream) {
  (void)in_sizes; (void)n_in; (void)out_size; (void)ws_size;
  const float* x    = (const float*)d_in[0];
  const float* Wq   = (const float*)d_in[1];
  const float* bq   = (const float*)d_in[2];
  const float* Wk   = (const float*)d_in[3];
  const float* bk   = (const float*)d_in[4];
  const float* Wv   = (const float*)d_in[5];
  const float* bv   = (const float*)d_in[6];
  const float* gam  = (const float*)d_in[7];
  const float* temp = (const float*)d_in[8];
  float* out = (float*)d_out;

  char* ws = (char*)d_ws;
  unsigned short* vbf = (unsigned short*)ws;                       // 16 MB (tiled layout)
  unsigned short* qbf = (unsigned short*)(ws + (16u << 20));       // 2 MB
  unsigned short* kbf = (unsigned short*)(ws + (18u << 20));       // 2 MB
  unsigned short* wqb = (unsigned short*)(ws + (20u << 20));       // 16 KB
  unsigned short* wkb = wqb + 8192;                                // 16 KB
  unsigned short* wvb = wkb + 8192;                                // 128 KB
  float* ssq = (float*)(wvb + 65536);                              // 2 KB

  prep_kernel<<<dim3(288), dim3(256), 0, stream>>>(Wq, Wk, Wv, wqb, wkb, wvb, ssq);
  qkv_kernel<<<dim3(512), dim3(256), 0, stream>>>(x, wqb, wkb, wvb, bq, bk, bv, qbf, kbf, vbf, ssq);
  attn_kernel<<<dim3(512), dim3(512), 0, stream>>>(qbf, kbf, vbf, ssq, temp, x, gam, out);
}

// Round 14
// 211.815 us; speedup vs baseline: 1.1197x; 1.1197x over previous
//
#include <hip/hip_runtime.h>
#include <hip/hip_bf16.h>
#include <math.h>

typedef __attribute__((ext_vector_type(8))) short short8;
typedef __attribute__((ext_vector_type(4))) float floatx4;
typedef __attribute__((ext_vector_type(16))) float floatx16;

#define B_ 8
#define C_ 256
#define N_ 4096
#define LOG2E 1.4426950408889634f
#define XSTRIDE 532   // qkv LDS row stride bytes (256 bf16 + 20B pad)

static __device__ __forceinline__ unsigned short f2bf(float f) {
  union { float f; unsigned int u; } v; v.f = f;
  unsigned int u = v.u;
  u += 0x7FFFu + ((u >> 16) & 1u);   // RNE
  return (unsigned short)(u >> 16);
}
static __device__ __forceinline__ float bf2f(unsigned short h) {
  union { unsigned int u; float f; } v; v.u = ((unsigned int)h) << 16; return v.f;
}
// truncation pack of two positive f32 -> bf16x2 in ONE v_perm_b32 (lo = a, hi = b)
static __device__ __forceinline__ unsigned int pk2(float a, float b) {
  return __builtin_amdgcn_perm(__float_as_uint(b), __float_as_uint(a), 0x07060302u);
}

// ---------------- kernel 0: weight convert + ssq zero ----------------
__global__ void prep_kernel(const float* __restrict__ Wq, const float* __restrict__ Wk,
                            const float* __restrict__ Wv,
                            unsigned short* __restrict__ wqb, unsigned short* __restrict__ wkb,
                            unsigned short* __restrict__ wvb, float* __restrict__ ssq) {
  int t = blockIdx.x * 256 + threadIdx.x;
  if (t < 512) ssq[t] = 0.0f;
  if (t < 8192) { wqb[t] = f2bf(Wq[t]); wkb[t] = f2bf(Wk[t]); }
  int tv = t - 8192;
  if (tv >= 0 && tv < 65536) wvb[tv] = f2bf(Wv[tv]);
}

// ---------------- kernel 1: QKV GEMM, coalesced transpose-staged x ----------------
// V written in FRAGMENT-NATIVE tiled layout: elem[(n>>3)*2048 + cv*8 + (n&7)]
__launch_bounds__(256, 2)
__global__ void qkv_kernel(const float* __restrict__ x,
                           const unsigned short* __restrict__ wqb,
                           const unsigned short* __restrict__ wkb,
                           const unsigned short* __restrict__ wvb,
                           const float* __restrict__ bq, const float* __restrict__ bk,
                           const float* __restrict__ bv,
                           unsigned short* __restrict__ qbf, unsigned short* __restrict__ kbf,
                           unsigned short* __restrict__ vbf, float* __restrict__ ssq) {
  __shared__ __align__(16) char Xt[64 * XSTRIDE];   // [64 n][256 c bf16 + pad]
  int b = blockIdx.x & 7;
  int nblk = blockIdx.x >> 3;
  int tid = threadIdx.x;
  int w = tid >> 6, lane = tid & 63;
  int r = lane & 15, g = lane >> 4;
  int n0 = nblk * 64;
  int q = tid & 15, cpl = tid >> 4;

  // ---- stage x tile: [c][n] fp32 -> [n][c] bf16 (transpose via regs) ----
  const float* xb = x + ((size_t)b << 20) + n0 + q * 4;
  #pragma unroll
  for (int p = 0; p < 8; ++p) {
    int cp = p * 16 + cpl;                         // c-pair index: c = 2cp, 2cp+1
    const float* s0 = xb + ((size_t)(2 * cp) << 12);
    float4 a  = *(const float4*)s0;
    float4 bb = *(const float4*)(s0 + 4096);
    char* dst = Xt + cp * 4;
    *(unsigned int*)(dst + (q * 4 + 0) * XSTRIDE) = pk2(a.x, bb.x);
    *(unsigned int*)(dst + (q * 4 + 1) * XSTRIDE) = pk2(a.y, bb.y);
    *(unsigned int*)(dst + (q * 4 + 2) * XSTRIDE) = pk2(a.z, bb.z);
    *(unsigned int*)(dst + (q * 4 + 3) * XSTRIDE) = pk2(a.w, bb.w);
  }
  __syncthreads();

  // ---- fragments: B[k=c][col=n], lane col = n0 + w*16 + r, k = ks*32 + g*8 + j ----
  short8 xf[8];
  #pragma unroll
  for (int ks = 0; ks < 8; ++ks) {
    const char* src = Xt + (w * 16 + r) * XSTRIDE + (ks * 32 + g * 8) * 2;
    union { unsigned int u[4]; short8 s8; } t;
    t.u[0] = *(const unsigned int*)(src);
    t.u[1] = *(const unsigned int*)(src + 4);
    t.u[2] = *(const unsigned int*)(src + 8);
    t.u[3] = *(const unsigned int*)(src + 12);
    xf[ks] = t.s8;
  }
  int nw = n0 + w * 16;
  floatx4 zero = {0.f, 0.f, 0.f, 0.f};

  // ---- V: 16 output tiles, tiled-layout writes ----
  unsigned short* vt = vbf + (size_t)b * C_ * N_;
  #pragma unroll 2
  for (int ot = 0; ot < 16; ++ot) {
    floatx4 acc = zero;
    #pragma unroll
    for (int ks = 0; ks < 8; ++ks) {
      short8 af = *(const short8*)&wvb[(ot * 16 + r) * 256 + ks * 32 + g * 8];
      acc = __builtin_amdgcn_mfma_f32_16x16x32_bf16(af, xf[ks], acc, 0, 0, 0);
    }
    #pragma unroll
    for (int rr = 0; rr < 4; ++rr) {
      int oc = ot * 16 + g * 4 + rr;
      int n = nw + r;
      vt[(size_t)(n >> 3) * 2048 + oc * 8 + (n & 7)] = f2bf(acc[rr] + bv[oc]);
    }
  }
  // ---- Q then K (2 tiles each), RAW (normalization folded into attn) ----
  #pragma unroll 1
  for (int qk = 0; qk < 2; ++qk) {
    const unsigned short* wb = qk ? wkb : wqb;
    const float* bias = qk ? bk : bq;
    unsigned short* dst = qk ? kbf : qbf;
    int sbase = qk ? 256 : 0;
    #pragma unroll 2
    for (int ot = 0; ot < 2; ++ot) {
      floatx4 acc = zero;
      #pragma unroll
      for (int ks = 0; ks < 8; ++ks) {
        short8 af = *(const short8*)&wb[(ot * 16 + r) * 256 + ks * 32 + g * 8];
        acc = __builtin_amdgcn_mfma_f32_16x16x32_bf16(af, xf[ks], acc, 0, 0, 0);
      }
      #pragma unroll
      for (int rr = 0; rr < 4; ++rr) {
        int oc = ot * 16 + g * 4 + rr;
        float val = acc[rr] + bias[oc];
        dst[(size_t)(b * N_ + nw + r) * 32 + oc] = f2bf(val);
        float s = val * val;               // reduce over the 16 n (lanes r)
        s += __shfl_xor(s, 1);
        s += __shfl_xor(s, 2);
        s += __shfl_xor(s, 4);
        s += __shfl_xor(s, 8);
        if (r == 0) atomicAdd(&ssq[sbase + b * 32 + oc], s);
      }
    }
  }
}

// ---------------- kernel 2: BARRIER-FREE 32x32-MFMA attention ----------------
// Zero LDS, zero __syncthreads. Block: 256 thr = 4 independent waves (ms 2 x cvh 2),
// m=64 rows, grid 512 (2 blocks/CU). Each wave: K frags direct from global (lane (c,h)
// reads 16B at row*64B + h*16B -> wave covers one contiguous 2KB block, L2-resident),
// V frags from the fragment-native tiled layout (2x512B per load). Both register
// double-buffered with a FULL-TILE prefetch distance; pointers increment (no addr VALU).
// Waves drift freely -> latency hidden in-wave, no lockstep drain.
__launch_bounds__(256, 2)
__global__ void attn_kernel(const unsigned short* __restrict__ qbf,
                            const unsigned short* __restrict__ kbf,
                            const unsigned short* __restrict__ vbf,
                            const float* __restrict__ ssq, const float* __restrict__ temp,
                            const float* __restrict__ x, const float* __restrict__ gamma,
                            float* __restrict__ out) {
  int b = blockIdx.x & 7, mblk = blockIdx.x >> 3;       // mblk in [0,64)
  int tid = threadIdx.x;
  int w = tid >> 6, lane = tid & 63, c = lane & 31, h = lane >> 5;
  int ms = w & 1, cvh = w >> 1;                         // 4 waves: ms(2) x cvh(2)
  const unsigned short* qb = qbf + (size_t)b * N_ * 32;
  const unsigned short* kb = kbf + (size_t)b * N_ * 32;
  const unsigned short* vt = vbf + (size_t)b * C_ * N_;
  int mrow = mblk * 64 + ms * 32 + c;                   // this lane's global m (column)
  int tdiag = mblk * 2 + ms;

  // ---- Q fragments with folded per-channel scale: invt*log2e/(||q_c||*||k_c||) ----
  float invt = LOG2E / (temp[0] + 1e-6f);
  short8 q0r = *(const short8*)&qb[mrow * 32 + h * 8];
  short8 q1r = *(const short8*)&qb[mrow * 32 + 16 + h * 8];
  short8 qf0, qf1;
  #pragma unroll
  for (int j = 0; j < 8; ++j) {
    int ch0 = h * 8 + j, ch1 = 16 + h * 8 + j;
    float s0 = invt * rsqrtf(fmaxf(ssq[b * 32 + ch0] * ssq[256 + b * 32 + ch0], 1e-24f));
    float s1 = invt * rsqrtf(fmaxf(ssq[b * 32 + ch1] * ssq[256 + b * 32 + ch1], 1e-24f));
    ((unsigned short*)&qf0)[j] = f2bf(bf2f(((const unsigned short*)&q0r)[j]) * s0);
    ((unsigned short*)&qf1)[j] = f2bf(bf2f(((const unsigned short*)&q1r)[j]) * s1);
  }

  // K fragment pointer: row n = t*32 + c, channels h*8.. / 16+h*8..; +1024 elems/tile
  const unsigned short* kp = kb + (size_t)c * 32 + h * 8;
  // V fragment pointers (tiled layout): +8192 elems/tile, cvt*256 elem imm offsets
  const unsigned short* vp0 = vt + h * 2048 + (cvh * 128 + c) * 8;
  const unsigned short* vp1 = vp0 + 4096;

  floatx16 minit;                                        // C-init = -2*log2e (softmax shift)
  #pragma unroll
  for (int i = 0; i < 16; ++i) minit[i] = -2.0f * LOG2E;
  floatx16 zero16 = {0,0,0,0,0,0,0,0,0,0,0,0,0,0,0,0};
  floatx16 acc[4] = {zero16, zero16, zero16, zero16};    // [cvt] D[cv 32][m 32]
  float Lp = 0.0f;
  short8 kfA[2], kfB[2], afA[8], afB[8];

  // ---- prologue: load K(0), V(0) ----
  kfA[0] = *(const short8*)kp;
  kfA[1] = *(const short8*)(kp + 16);
  kp += 1024;
  #pragma unroll
  for (int k = 0; k < 8; ++k)
    afA[k] = *(const short8*)(((k >> 2) ? vp1 : vp0) + (k & 3) * 256);
  vp0 += 8192; vp1 += 8192;

  auto body = [&](int t, short8 (&kfC)[2], short8 (&kfN)[2],
                  short8 (&afC)[8], short8 (&afN)[8]) {
    if (t + 1 < 128) {                                  // issue K(t+1), V(t+1)
      kfN[0] = *(const short8*)kp;
      kfN[1] = *(const short8*)(kp + 16);
      kp += 1024;
      #pragma unroll
      for (int k = 0; k < 8; ++k)
        afN[k] = *(const short8*)(((k >> 2) ? vp1 : vp0) + (k & 3) * 256);
      vp0 += 8192; vp1 += 8192;
    }
    // QK^T (K loaded a full tile ago)
    floatx16 s = __builtin_amdgcn_mfma_f32_32x32x16_bf16(kfC[0], qf0, minit, 0, 0, 0);
    s = __builtin_amdgcn_mfma_f32_32x32x16_bf16(kfC[1], qf1, s, 0, 0, 0);
    if (t == tdiag && ((c >> 2) & 1) == h)              // +I where global n == m
      s[(c & 3) | ((c >> 3) << 2)] += LOG2E;
    float p[16];
    float ls = 0.0f;
    #pragma unroll
    for (int i = 0; i < 16; ++i) {
      p[i] = __builtin_amdgcn_exp2f(s[i]);
      ls += p[i];
    }
    Lp += ls;
    #pragma unroll
    for (int t16 = 0; t16 < 2; ++t16) {
      unsigned int q0 = pk2(p[8*t16+0], p[8*t16+1]);
      unsigned int q1 = pk2(p[8*t16+2], p[8*t16+3]);
      unsigned int q2 = pk2(p[8*t16+4], p[8*t16+5]);
      unsigned int q3 = pk2(p[8*t16+6], p[8*t16+7]);
      // swap(vdst,vsrc): vdst[0:31] <-> vsrc[32:63]
      asm volatile("v_permlane32_swap_b32 %0, %1" : "+v"(q2), "+v"(q0));
      asm volatile("v_permlane32_swap_b32 %0, %1" : "+v"(q3), "+v"(q1));
      union { unsigned int u[4]; short8 s8; } bf;
      bf.u[0] = q0; bf.u[1] = q1; bf.u[2] = q2; bf.u[3] = q3;
      #pragma unroll
      for (int cvt = 0; cvt < 4; ++cvt)
        acc[cvt] = __builtin_amdgcn_mfma_f32_32x32x16_bf16(afC[t16 * 4 + cvt], bf.s8, acc[cvt], 0, 0, 0);
    }
  };

  #pragma unroll 1
  for (int t = 0; t < 128; t += 2) {
    body(t, kfA, kfB, afA, afB);
    body(t + 1, kfB, kfA, afB, afA);
  }

  // denominator: lane holds half the n-sum for column m; partner (lane^32) has the rest
  Lp += __shfl_xor(Lp, 32);
  float linv = 1.0f / Lp;
  float gam = gamma[0];
  #pragma unroll
  for (int cvt = 0; cvt < 4; ++cvt)
    #pragma unroll
    for (int i = 0; i < 16; ++i) {
      int cv = cvh * 128 + cvt * 32 + (i & 3) + 8 * (i >> 2) + 4 * h;
      size_t idx = ((size_t)(b * C_ + cv) << 12) + mrow;
      out[idx] = gam * acc[cvt][i] * linv + x[idx];
    }
}

extern "C" void kernel_launch(void* const* d_in, const int* in_sizes, int n_in,
                              void* d_out, int out_size, void* d_ws, size_t ws_size,
                              hipStream_t stream) {
  (void)in_sizes; (void)n_in; (void)out_size; (void)ws_size;
  const float* x    = (const float*)d_in[0];
  const float* Wq   = (const float*)d_in[1];
  const float* bq   = (const float*)d_in[2];
  const float* Wk   = (const float*)d_in[3];
  const float* bk   = (const float*)d_in[4];
  const float* Wv   = (const float*)d_in[5];
  const float* bv   = (const float*)d_in[6];
  const float* gam  = (const float*)d_in[7];
  const float* temp = (const float*)d_in[8];
  float* out = (float*)d_out;

  char* ws = (char*)d_ws;
  unsigned short* vbf = (unsigned short*)ws;                       // 16 MB (tiled layout)
  unsigned short* qbf = (unsigned short*)(ws + (16u << 20));       // 2 MB
  unsigned short* kbf = (unsigned short*)(ws + (18u << 20));       // 2 MB
  unsigned short* wqb = (unsigned short*)(ws + (20u << 20));       // 16 KB
  unsigned short* wkb = wqb + 8192;                                // 16 KB
  unsigned short* wvb = wkb + 8192;                                // 128 KB
  float* ssq = (float*)(wvb + 65536);                              // 2 KB

  prep_kernel<<<dim3(288), dim3(256), 0, stream>>>(Wq, Wk, Wv, wqb, wkb, wvb, ssq);
  qkv_kernel<<<dim3(512), dim3(256), 0, stream>>>(x, wqb, wkb, wvb, bq, bk, bv, qbf, kbf, vbf, ssq);
  attn_kernel<<<dim3(512), dim3(256), 0, stream>>>(qbf, kbf, vbf, ssq, temp, x, gam, out);
}

// Round 15
// 181.351 us; speedup vs baseline: 1.3078x; 1.1680x over previous
//
#include <hip/hip_runtime.h>
#include <hip/hip_bf16.h>
#include <math.h>

typedef __attribute__((ext_vector_type(8))) short short8;
typedef __attribute__((ext_vector_type(4))) float floatx4;
typedef __attribute__((ext_vector_type(16))) float floatx16;

#define B_ 8
#define C_ 256
#define N_ 4096
#define LOG2E 1.4426950408889634f
#define XSTRIDE 548   // qkv LDS row stride bytes (137 dw; 137%32=9 -> <=2-way banks r/w)

static __device__ __forceinline__ unsigned short f2bf(float f) {
  union { float f; unsigned int u; } v; v.f = f;
  unsigned int u = v.u;
  u += 0x7FFFu + ((u >> 16) & 1u);   // RNE
  return (unsigned short)(u >> 16);
}
static __device__ __forceinline__ float bf2f(unsigned short h) {
  union { unsigned int u; float f; } v; v.u = ((unsigned int)h) << 16; return v.f;
}
// truncation pack of two positive f32 -> bf16x2 in ONE v_perm_b32 (lo = a, hi = b)
static __device__ __forceinline__ unsigned int pk2(float a, float b) {
  return __builtin_amdgcn_perm(__float_as_uint(b), __float_as_uint(a), 0x07060302u);
}

// ---------------- kernel 0: weight convert + ssq zero ----------------
__global__ void prep_kernel(const float* __restrict__ Wq, const float* __restrict__ Wk,
                            const float* __restrict__ Wv,
                            unsigned short* __restrict__ wqb, unsigned short* __restrict__ wkb,
                            unsigned short* __restrict__ wvb, float* __restrict__ ssq) {
  int t = blockIdx.x * 256 + threadIdx.x;
  if (t < 512) ssq[t] = 0.0f;
  if (t < 8192) { wqb[t] = f2bf(Wq[t]); wkb[t] = f2bf(Wk[t]); }
  int tv = t - 8192;
  if (tv >= 0 && tv < 65536) wvb[tv] = f2bf(Wv[tv]);
}

// ---------------- kernel 1: QKV GEMM, 8-wave pipelined single-pass ----------------
// Block: 512 thr = 8 waves = nh(4: which 16 n-cols) x ch(2: V tiles 0-7 + Q / 8-15 + K).
// x staged ONCE (64n x 256c, coalesced float4 -> pk2 -> b32, one barrier). Per wave:
// 10 tiles x 8 MFMA, W fragments software-pipelined at half-tile granularity (4 frags
// loading while 4 MFMA run) -> L2 latency hidden; tile base = ptr + t*4096 (no addr VALU).
// V written in fragment-native tiled layout: elem[(n>>3)*2048 + cv*8 + (n&7)].
__launch_bounds__(512, 4)
__global__ void qkv_kernel(const float* __restrict__ x,
                           const unsigned short* __restrict__ wqb,
                           const unsigned short* __restrict__ wkb,
                           const unsigned short* __restrict__ wvb,
                           const float* __restrict__ bq, const float* __restrict__ bk,
                           const float* __restrict__ bv,
                           unsigned short* __restrict__ qbf, unsigned short* __restrict__ kbf,
                           unsigned short* __restrict__ vbf, float* __restrict__ ssq) {
  __shared__ __align__(16) char Xt[64 * XSTRIDE];   // [64 n][256 c bf16 + pad]
  int b = blockIdx.x & 7;
  int nblk = blockIdx.x >> 3;
  int tid = threadIdx.x;
  int w = tid >> 6, lane = tid & 63;
  int r = lane & 15, g = lane >> 4;
  int nh = w & 3, ch = w >> 2;
  int n0 = nblk * 64;

  // ---- stage x tile: [c][n] fp32 -> [n][c] bf16 (transpose via regs), coalesced ----
  {
    int q = tid & 15, cpw = tid >> 4;               // q: float4 col, cpw: c-pair group
    const float* xb = x + ((size_t)b << 20) + n0 + q * 4;
    #pragma unroll
    for (int p = 0; p < 4; ++p) {
      int cp = p * 32 + cpw;                        // c-pair: c = 2cp, 2cp+1
      const float* s0 = xb + ((size_t)(2 * cp) << 12);
      float4 a  = *(const float4*)s0;
      float4 bb = *(const float4*)(s0 + 4096);
      char* dst = Xt + cp * 4;
      *(unsigned int*)(dst + (q * 4 + 0) * XSTRIDE) = pk2(a.x, bb.x);
      *(unsigned int*)(dst + (q * 4 + 1) * XSTRIDE) = pk2(a.y, bb.y);
      *(unsigned int*)(dst + (q * 4 + 2) * XSTRIDE) = pk2(a.z, bb.z);
      *(unsigned int*)(dst + (q * 4 + 3) * XSTRIDE) = pk2(a.w, bb.w);
    }
  }
  __syncthreads();

  // ---- x fragments: col n = n0 + nh*16 + r, k = ks*32 + g*8 + j ----
  short8 xf[8];
  #pragma unroll
  for (int ks = 0; ks < 8; ++ks) {
    const char* src = Xt + (nh * 16 + r) * XSTRIDE + (ks * 32 + g * 8) * 2;
    union { unsigned int u[4]; short8 s8; } t;
    t.u[0] = *(const unsigned int*)(src);
    t.u[1] = *(const unsigned int*)(src + 4);
    t.u[2] = *(const unsigned int*)(src + 8);
    t.u[3] = *(const unsigned int*)(src + 12);
    xf[ks] = t.s8;
  }
  int nw = n0 + nh * 16;
  floatx4 zero = {0.f, 0.f, 0.f, 0.f};
  unsigned short* vt = vbf + (size_t)b * C_ * N_;
  const unsigned short* wqk = ch ? wkb : wqb;
  const float* bias = ch ? bk : bq;
  unsigned short* qkdst = ch ? kbf : qbf;
  int sbase = ch ? 256 : 0;

  // tile bases: t<8 -> V tile ch*8+t ; t=8,9 -> Q/K tile t-8. stride 4096 elems/tile.
  const unsigned short* vwb = wvb + (size_t)(ch * 128 + r) * 256 + g * 8;
  const unsigned short* qwb = wqk + (size_t)r * 256 + g * 8;

  short8 wf[2][4];
  #pragma unroll
  for (int j = 0; j < 4; ++j) wf[0][j] = *(const short8*)(vwb + j * 32);

  #pragma unroll
  for (int t = 0; t < 10; ++t) {
    const unsigned short* curb = (t < 8) ? (vwb + t * 4096) : (qwb + (t - 8) * 4096);
    const unsigned short* nxtb = (t < 7) ? (vwb + (t + 1) * 4096)
                                         : ((t < 9) ? (qwb + (t - 7) * 4096) : curb);
    floatx4 acc = zero;
    // half 0: prefetch half 1, MFMA ks 0..3
    #pragma unroll
    for (int j = 0; j < 4; ++j) wf[1][j] = *(const short8*)(curb + (4 + j) * 32);
    #pragma unroll
    for (int j = 0; j < 4; ++j)
      acc = __builtin_amdgcn_mfma_f32_16x16x32_bf16(wf[0][j], xf[j], acc, 0, 0, 0);
    // half 1: prefetch next tile half 0, MFMA ks 4..7
    #pragma unroll
    for (int j = 0; j < 4; ++j) wf[0][j] = *(const short8*)(nxtb + j * 32);
    #pragma unroll
    for (int j = 0; j < 4; ++j)
      acc = __builtin_amdgcn_mfma_f32_16x16x32_bf16(wf[1][j], xf[4 + j], acc, 0, 0, 0);

    if (t < 8) {                                    // V tile: tiled-layout stores
      int otile = ch * 8 + t;
      #pragma unroll
      for (int rr = 0; rr < 4; ++rr) {
        int oc = otile * 16 + g * 4 + rr;
        int n = nw + r;
        vt[(size_t)(n >> 3) * 2048 + oc * 8 + (n & 7)] = f2bf(acc[rr] + bv[oc]);
      }
    } else {                                        // Q (ch=0) / K (ch=1) tile
      #pragma unroll
      for (int rr = 0; rr < 4; ++rr) {
        int oc = (t - 8) * 16 + g * 4 + rr;
        float val = acc[rr] + bias[oc];
        qkdst[(size_t)(b * N_ + nw + r) * 32 + oc] = f2bf(val);
        float s = val * val;                        // reduce over the 16 n (lanes r)
        s += __shfl_xor(s, 1);
        s += __shfl_xor(s, 2);
        s += __shfl_xor(s, 4);
        s += __shfl_xor(s, 8);
        if (r == 0) atomicAdd(&ssq[sbase + b * 32 + oc], s);
      }
    }
  }
}

// ---------------- kernel 2: BARRIER-FREE 32x32-MFMA attention (r14, unchanged) ----------------
__launch_bounds__(256, 2)
__global__ void attn_kernel(const unsigned short* __restrict__ qbf,
                            const unsigned short* __restrict__ kbf,
                            const unsigned short* __restrict__ vbf,
                            const float* __restrict__ ssq, const float* __restrict__ temp,
                            const float* __restrict__ x, const float* __restrict__ gamma,
                            float* __restrict__ out) {
  int b = blockIdx.x & 7, mblk = blockIdx.x >> 3;       // mblk in [0,64)
  int tid = threadIdx.x;
  int w = tid >> 6, lane = tid & 63, c = lane & 31, h = lane >> 5;
  int ms = w & 1, cvh = w >> 1;                         // 4 waves: ms(2) x cvh(2)
  const unsigned short* qb = qbf + (size_t)b * N_ * 32;
  const unsigned short* kb = kbf + (size_t)b * N_ * 32;
  const unsigned short* vt = vbf + (size_t)b * C_ * N_;
  int mrow = mblk * 64 + ms * 32 + c;                   // this lane's global m (column)
  int tdiag = mblk * 2 + ms;

  // ---- Q fragments with folded per-channel scale: invt*log2e/(||q_c||*||k_c||) ----
  float invt = LOG2E / (temp[0] + 1e-6f);
  short8 q0r = *(const short8*)&qb[mrow * 32 + h * 8];
  short8 q1r = *(const short8*)&qb[mrow * 32 + 16 + h * 8];
  short8 qf0, qf1;
  #pragma unroll
  for (int j = 0; j < 8; ++j) {
    int ch0 = h * 8 + j, ch1 = 16 + h * 8 + j;
    float s0 = invt * rsqrtf(fmaxf(ssq[b * 32 + ch0] * ssq[256 + b * 32 + ch0], 1e-24f));
    float s1 = invt * rsqrtf(fmaxf(ssq[b * 32 + ch1] * ssq[256 + b * 32 + ch1], 1e-24f));
    ((unsigned short*)&qf0)[j] = f2bf(bf2f(((const unsigned short*)&q0r)[j]) * s0);
    ((unsigned short*)&qf1)[j] = f2bf(bf2f(((const unsigned short*)&q1r)[j]) * s1);
  }

  // K fragment pointer: row n = t*32 + c, channels h*8.. / 16+h*8..; +1024 elems/tile
  const unsigned short* kp = kb + (size_t)c * 32 + h * 8;
  // V fragment pointers (tiled layout): +8192 elems/tile, cvt*256 elem imm offsets
  const unsigned short* vp0 = vt + h * 2048 + (cvh * 128 + c) * 8;
  const unsigned short* vp1 = vp0 + 4096;

  floatx16 minit;                                        // C-init = -2*log2e (softmax shift)
  #pragma unroll
  for (int i = 0; i < 16; ++i) minit[i] = -2.0f * LOG2E;
  floatx16 zero16 = {0,0,0,0,0,0,0,0,0,0,0,0,0,0,0,0};
  floatx16 acc[4] = {zero16, zero16, zero16, zero16};    // [cvt] D[cv 32][m 32]
  float Lp = 0.0f;
  short8 kfA[2], kfB[2], afA[8], afB[8];

  // ---- prologue: load K(0), V(0) ----
  kfA[0] = *(const short8*)kp;
  kfA[1] = *(const short8*)(kp + 16);
  kp += 1024;
  #pragma unroll
  for (int k = 0; k < 8; ++k)
    afA[k] = *(const short8*)(((k >> 2) ? vp1 : vp0) + (k & 3) * 256);
  vp0 += 8192; vp1 += 8192;

  auto body = [&](int t, short8 (&kfC)[2], short8 (&kfN)[2],
                  short8 (&afC)[8], short8 (&afN)[8]) {
    if (t + 1 < 128) {                                  // issue K(t+1), V(t+1)
      kfN[0] = *(const short8*)kp;
      kfN[1] = *(const short8*)(kp + 16);
      kp += 1024;
      #pragma unroll
      for (int k = 0; k < 8; ++k)
        afN[k] = *(const short8*)(((k >> 2) ? vp1 : vp0) + (k & 3) * 256);
      vp0 += 8192; vp1 += 8192;
    }
    // QK^T (K loaded a full tile ago)
    floatx16 s = __builtin_amdgcn_mfma_f32_32x32x16_bf16(kfC[0], qf0, minit, 0, 0, 0);
    s = __builtin_amdgcn_mfma_f32_32x32x16_bf16(kfC[1], qf1, s, 0, 0, 0);
    if (t == tdiag && ((c >> 2) & 1) == h)              // +I where global n == m
      s[(c & 3) | ((c >> 3) << 2)] += LOG2E;
    float p[16];
    float ls = 0.0f;
    #pragma unroll
    for (int i = 0; i < 16; ++i) {
      p[i] = __builtin_amdgcn_exp2f(s[i]);
      ls += p[i];
    }
    Lp += ls;
    #pragma unroll
    for (int t16 = 0; t16 < 2; ++t16) {
      unsigned int q0 = pk2(p[8*t16+0], p[8*t16+1]);
      unsigned int q1 = pk2(p[8*t16+2], p[8*t16+3]);
      unsigned int q2 = pk2(p[8*t16+4], p[8*t16+5]);
      unsigned int q3 = pk2(p[8*t16+6], p[8*t16+7]);
      // swap(vdst,vsrc): vdst[0:31] <-> vsrc[32:63]
      asm volatile("v_permlane32_swap_b32 %0, %1" : "+v"(q2), "+v"(q0));
      asm volatile("v_permlane32_swap_b32 %0, %1" : "+v"(q3), "+v"(q1));
      union { unsigned int u[4]; short8 s8; } bf;
      bf.u[0] = q0; bf.u[1] = q1; bf.u[2] = q2; bf.u[3] = q3;
      #pragma unroll
      for (int cvt = 0; cvt < 4; ++cvt)
        acc[cvt] = __builtin_amdgcn_mfma_f32_32x32x16_bf16(afC[t16 * 4 + cvt], bf.s8, acc[cvt], 0, 0, 0);
    }
  };

  #pragma unroll 1
  for (int t = 0; t < 128; t += 2) {
    body(t, kfA, kfB, afA, afB);
    body(t + 1, kfB, kfA, afB, afA);
  }

  // denominator: lane holds half the n-sum for column m; partner (lane^32) has the rest
  Lp += __shfl_xor(Lp, 32);
  float linv = 1.0f / Lp;
  float gam = gamma[0];
  #pragma unroll
  for (int cvt = 0; cvt < 4; ++cvt)
    #pragma unroll
    for (int i = 0; i < 16; ++i) {
      int cv = cvh * 128 + cvt * 32 + (i & 3) + 8 * (i >> 2) + 4 * h;
      size_t idx = ((size_t)(b * C_ + cv) << 12) + mrow;
      out[idx] = gam * acc[cvt][i] * linv + x[idx];
    }
}

extern "C" void kernel_launch(void* const* d_in, const int* in_sizes, int n_in,
                              void* d_out, int out_size, void* d_ws, size_t ws_size,
                              hipStream_t stream) {
  (void)in_sizes; (void)n_in; (void)out_size; (void)ws_size;
  const float* x    = (const float*)d_in[0];
  const float* Wq   = (const float*)d_in[1];
  const float* bq   = (const float*)d_in[2];
  const float* Wk   = (const float*)d_in[3];
  const float* bk   = (const float*)d_in[4];
  const float* Wv   = (const float*)d_in[5];
  const float* bv   = (const float*)d_in[6];
  const float* gam  = (const float*)d_in[7];
  const float* temp = (const float*)d_in[8];
  float* out = (float*)d_out;

  char* ws = (char*)d_ws;
  unsigned short* vbf = (unsigned short*)ws;                       // 16 MB (tiled layout)
  unsigned short* qbf = (unsigned short*)(ws + (16u << 20));       // 2 MB
  unsigned short* kbf = (unsigned short*)(ws + (18u << 20));       // 2 MB
  unsigned short* wqb = (unsigned short*)(ws + (20u << 20));       // 16 KB
  unsigned short* wkb = wqb + 8192;                                // 16 KB
  unsigned short* wvb = wkb + 8192;                                // 128 KB
  float* ssq = (float*)(wvb + 65536);                              // 2 KB

  prep_kernel<<<dim3(288), dim3(256), 0, stream>>>(Wq, Wk, Wv, wqb, wkb, wvb, ssq);
  qkv_kernel<<<dim3(512), dim3(512), 0, stream>>>(x, wqb, wkb, wvb, bq, bk, bv, qbf, kbf, vbf, ssq);
  attn_kernel<<<dim3(512), dim3(256), 0, stream>>>(qbf, kbf, vbf, ssq, temp, x, gam, out);
}